// Round 1
// baseline (60.130 us; speedup 1.0000x reference)
//
#include <hip/hip_runtime.h>
#include <math.h>

// WindAdjacency: A[b,i,j] = mask*exp(-D/R)*exp(max(cos(ang),0))*speed, row-normalized.
// B=8, N=2048. One block per (b,i) row; 256 threads x 8 elements each.

#define NN 2048
#define BB 8

__global__ __launch_bounds__(256) void wind_adj_kernel(
    const float* __restrict__ wind_feats,  // [B,N,2]
    const float* __restrict__ D,           // [N,N]
    const float* __restrict__ Theta,       // [N,N]
    float* __restrict__ out)               // [B,N,N]
{
    constexpr float PI_F     = 3.14159265358979323846f;   // 0x40490FDB
    constexpr float TWO_PI_F = 6.28318530717958647692f;   // 0x40C90FDB
    constexpr float CONE_F   = 0.78539816339744830962f;   // f32(pi/4), matches jax compare
    constexpr float R_INV    = 1.0f / 150.0f;
    constexpr float EPS      = 1e-8f;

    const int idx = blockIdx.x;        // = i*8 + b  (batch-blocks for same row adjacent)
    const int i   = idx >> 3;
    const int b   = idx & 7;
    const int tid = threadIdx.x;

    const float wind_speed = wind_feats[((size_t)b * NN + i) * 2 + 0];
    const float wind_dir   = wind_feats[((size_t)b * NN + i) * 2 + 1];
    float wind_to = wind_dir + PI_F;                 // ref: (dir + pi) % 2pi; dir in [0,1) so < 2pi
    if (wind_to >= TWO_PI_F) wind_to -= TWO_PI_F;    // safety, matches fp32 mod semantics here

    const float4* __restrict__ Drow = reinterpret_cast<const float4*>(D     + (size_t)i * NN);
    const float4* __restrict__ Trow = reinterpret_cast<const float4*>(Theta + (size_t)i * NN);
    float4* __restrict__ Orow = reinterpret_cast<float4*>(out + ((size_t)b * NN + i) * NN);

    const int j4 = tid * 2;            // first float4 index handled by this thread
    float vals[8];
    float psum = 0.0f;

    #pragma unroll
    for (int q = 0; q < 2; ++q) {
        float4 d4 = Drow[j4 + q];
        float4 t4 = Trow[j4 + q];
        #pragma unroll
        for (int e = 0; e < 4; ++e) {
            float dij = (&d4.x)[e];
            float th  = (&t4.x)[e];
            // ang = ((Theta - wind_to + pi) mod 2pi) - pi, exact f32 replication of ref
            float t = th - wind_to + PI_F;           // t in (-1, 2pi)
            t = (t < 0.0f) ? (t + TWO_PI_F) : t;     // mod 2pi for this range
            float ang = t - PI_F;                    // [-pi, pi)
            float align = fmaxf(__cosf(ang), 0.0f);
            float v = __expf(__builtin_fmaf(dij, -R_INV, align));  // exp(align - D/R)
            v = (fabsf(ang) <= CONE_F) ? v : 0.0f;   // cone mask (bit-exact f32 compare)
            int j = j4 * 4 + q * 4 + e;
            if (j == i) v = 0.0f;                    // no self loop
            vals[q * 4 + e] = v;
            psum += v;
        }
    }

    // block reduction: wave shfl then LDS across the 4 waves
    float s = psum;
    #pragma unroll
    for (int off = 32; off > 0; off >>= 1) s += __shfl_down(s, off);
    __shared__ float wsum[4];
    const int lane = tid & 63, wid = tid >> 6;
    if (lane == 0) wsum[wid] = s;
    __syncthreads();
    const float total = wsum[0] + wsum[1] + wsum[2] + wsum[3];

    // A = (base*speed) / (sum(base)*speed + eps)
    const float scale = wind_speed / (__builtin_fmaf(total, wind_speed, EPS));

    #pragma unroll
    for (int q = 0; q < 2; ++q) {
        float4 o;
        o.x = vals[q * 4 + 0] * scale;
        o.y = vals[q * 4 + 1] * scale;
        o.z = vals[q * 4 + 2] * scale;
        o.w = vals[q * 4 + 3] * scale;
        Orow[j4 + q] = o;
    }
}

extern "C" void kernel_launch(void* const* d_in, const int* in_sizes, int n_in,
                              void* d_out, int out_size, void* d_ws, size_t ws_size,
                              hipStream_t stream) {
    const float* wind_feats = (const float*)d_in[0];  // [8,2048,2]
    const float* D_ij       = (const float*)d_in[1];  // [2048,2048]
    const float* Theta_ij   = (const float*)d_in[2];  // [2048,2048]
    float* out = (float*)d_out;                       // [8,2048,2048]

    dim3 grid(BB * NN);   // 16384 blocks, one per (b,i) row; idx = i*8+b
    dim3 block(256);
    wind_adj_kernel<<<grid, block, 0, stream>>>(wind_feats, D_ij, Theta_ij, out);
}

// Round 2
// 34.385 us; speedup vs baseline: 1.7487x; 1.7487x over previous
//
#include <hip/hip_runtime.h>
#include <math.h>

// WindAdjacency: A[b,i,j] = mask*exp(align - D/R)*speed, row-normalized.
// B=8, N=2048. One block per row i computes ALL 8 batches:
//   - D/Theta row loaded once (vs 8x in round-1) -> 8x less L2/L3 read traffic
//   - f4 index = q*256+tid -> every ld/st instruction is a dense 1KB/wave segment

#define NN 2048
#define BB 8

__global__ __launch_bounds__(256) void wind_adj_kernel(
    const float* __restrict__ wind_feats,  // [B,N,2]
    const float* __restrict__ D,           // [N,N]
    const float* __restrict__ Theta,       // [N,N]
    float* __restrict__ out)               // [B,N,N]
{
    constexpr float PI_F     = 3.14159265358979323846f;
    constexpr float TWO_PI_F = 6.28318530717958647692f;
    constexpr float CONE_F   = 0.78539816339744830962f;  // f32(pi/4), matches jax compare
    constexpr float R_INV    = 1.0f / 150.0f;
    constexpr float EPS      = 1e-8f;

    const int i   = blockIdx.x;   // row
    const int tid = threadIdx.x;

    // wind params for all 8 batches (block-uniform loads -> broadcast)
    float wind_to[BB], speed[BB];
    #pragma unroll
    for (int b = 0; b < BB; ++b) {
        speed[b]  = wind_feats[((size_t)b * NN + i) * 2 + 0];
        float dir = wind_feats[((size_t)b * NN + i) * 2 + 1];
        float wt  = dir + PI_F;                 // dir in [0,1) so dir+pi < 2pi: mod is identity
        if (wt >= TWO_PI_F) wt -= TWO_PI_F;     // safety only
        wind_to[b] = wt;
    }

    const float4* __restrict__ Drow = reinterpret_cast<const float4*>(D     + (size_t)i * NN);
    const float4* __restrict__ Trow = reinterpret_cast<const float4*>(Theta + (size_t)i * NN);

    float vals[2][4][BB];   // [q][e][b], fully unrolled -> static indexing, stays in VGPRs
    float psum[BB];
    #pragma unroll
    for (int b = 0; b < BB; ++b) psum[b] = 0.0f;

    #pragma unroll
    for (int q = 0; q < 2; ++q) {
        const int f4 = q * 256 + tid;           // dense 1KB/wave per instruction
        float4 d4 = Drow[f4];
        float4 t4 = Trow[f4];
        #pragma unroll
        for (int e = 0; e < 4; ++e) {
            const float dij = (&d4.x)[e];
            const float th  = (&t4.x)[e];
            const int   j   = f4 * 4 + e;
            const float dterm = dij * (-R_INV);          // hoisted across batches
            const bool  diag  = (j == i);
            #pragma unroll
            for (int b = 0; b < BB; ++b) {
                // exact f32 replication of ref: ang = ((Theta - wind_to) + pi) mod 2pi - pi
                float t = th - wind_to[b] + PI_F;        // in (-1, 2pi]
                t = (t < 0.0f) ? (t + TWO_PI_F) : t;     // == np.mod for this range
                float ang = t - PI_F;
                float align = fmaxf(__cosf(ang), 0.0f);
                float v = __expf(align + dterm);         // exp(align - D/R)
                v = (fabsf(ang) <= CONE_F) ? v : 0.0f;   // cone mask, bit-exact compare
                v = diag ? 0.0f : v;                     // no self loop
                vals[q][e][b] = v;
                psum[b] += v;
            }
        }
    }

    // 8 parallel block reductions: wave butterfly, then LDS across the 4 waves
    #pragma unroll
    for (int b = 0; b < BB; ++b) {
        float s = psum[b];
        #pragma unroll
        for (int off = 32; off > 0; off >>= 1) s += __shfl_down(s, off);
        psum[b] = s;    // valid in lane 0 of each wave
    }
    __shared__ float wsum[4][BB];
    const int lane = tid & 63, wid = tid >> 6;
    if (lane == 0) {
        #pragma unroll
        for (int b = 0; b < BB; ++b) wsum[wid][b] = psum[b];
    }
    __syncthreads();

    float scale[BB];
    #pragma unroll
    for (int b = 0; b < BB; ++b) {
        const float total = wsum[0][b] + wsum[1][b] + wsum[2][b] + wsum[3][b];
        // A = (v*speed) / (sum(v)*speed + eps)
        scale[b] = speed[b] / __builtin_fmaf(total, speed[b], EPS);
    }

    #pragma unroll
    for (int b = 0; b < BB; ++b) {
        float4* __restrict__ Orow = reinterpret_cast<float4*>(out + ((size_t)b * NN + i) * NN);
        #pragma unroll
        for (int q = 0; q < 2; ++q) {
            float4 o;
            o.x = vals[q][0][b] * scale[b];
            o.y = vals[q][1][b] * scale[b];
            o.z = vals[q][2][b] * scale[b];
            o.w = vals[q][3][b] * scale[b];
            Orow[q * 256 + tid] = o;
        }
    }
}

extern "C" void kernel_launch(void* const* d_in, const int* in_sizes, int n_in,
                              void* d_out, int out_size, void* d_ws, size_t ws_size,
                              hipStream_t stream) {
    const float* wind_feats = (const float*)d_in[0];  // [8,2048,2]
    const float* D_ij       = (const float*)d_in[1];  // [2048,2048]
    const float* Theta_ij   = (const float*)d_in[2];  // [2048,2048]
    float* out = (float*)d_out;                       // [8,2048,2048]

    dim3 grid(NN);        // one block per row i, all 8 batches
    dim3 block(256);
    wind_adj_kernel<<<grid, block, 0, stream>>>(wind_feats, D_ij, Theta_ij, out);
}